// Round 2
// baseline (621.839 us; speedup 1.0000x reference)
//
#include <hip/hip_runtime.h>
#include <hip/hip_bf16.h>

// Problem constants
#define BB   128
#define NN   196
#define MM   (BB*NN)      // 25088
#define ENC  2048
#define ATT  512
#define DEC  512

using f32x4 = __attribute__((ext_vector_type(4))) float;
using s16x8 = __attribute__((ext_vector_type(8))) short;

__device__ __forceinline__ short f2bf(float f) {
    union { __hip_bfloat16 h; short s; } u;
    u.h = __float2bfloat16(f);
    return u.s;
}

// ---------------------------------------------------------------------------
// k0a: transpose+convert W_enc [2048][512] f32 -> Wt [512][2048] bf16
// ---------------------------------------------------------------------------
__global__ void transpose_convert_kernel(const float* __restrict__ W,
                                         unsigned short* __restrict__ Wt) {
    __shared__ float tile[32][33];
    const int a0 = blockIdx.x * 32;   // 16 blocks
    const int k0 = blockIdx.y * 32;   // 64 blocks
    const int tx = threadIdx.x & 31, ty = threadIdx.x >> 5;  // 32 x 8
    #pragma unroll
    for (int i = 0; i < 32; i += 8)
        tile[ty + i][tx] = W[(size_t)(k0 + ty + i) * ATT + a0 + tx];
    __syncthreads();
    #pragma unroll
    for (int i = 0; i < 32; i += 8) {
        union { __hip_bfloat16 h; unsigned short u; } v;
        v.h = __float2bfloat16(tile[tx][ty + i]);
        Wt[(size_t)(a0 + ty + i) * ENC + k0 + tx] = v.u;
    }
}

// ---------------------------------------------------------------------------
// k0b: att2[b][a] = dec[b] @ W_dec[:,a] + b_dec[a] + b_enc[a]
// grid (128, 8) x 256 threads: 64 cols x 4-way k-split per block.
// ---------------------------------------------------------------------------
__global__ void att2_kernel(const float* __restrict__ dec,
                            const float* __restrict__ Wd,
                            const float* __restrict__ bd,
                            const float* __restrict__ benc,
                            float* __restrict__ att2) {
    const int b  = blockIdx.x;          // 128
    const int c0 = blockIdx.y * 64;     // 8 chunks
    const int t  = threadIdx.x;         // 256
    const int cl = t & 63, kg = t >> 6; // col-local, k-group
    __shared__ float sdec[DEC];
    __shared__ float red[4][64];
    sdec[t]       = dec[b * DEC + t];
    sdec[t + 256] = dec[b * DEC + t + 256];
    __syncthreads();
    float acc = 0.f;
    const float* wp = Wd + c0 + cl;
    #pragma unroll 8
    for (int k = kg * 128; k < kg * 128 + 128; ++k)
        acc += sdec[k] * wp[(size_t)k * ATT];
    red[kg][cl] = acc;
    __syncthreads();
    if (t < 64) {
        float s = red[0][t] + red[1][t] + red[2][t] + red[3][t];
        att2[b * ATT + c0 + t] = s + bd[c0 + t] + benc[c0 + t];
    }
}

// ---------------------------------------------------------------------------
// k1: fused GEMM + bias + relu + dot(W_full) -> e_part[2][MM]
//   Register-only K-loop: NO LDS staging, NO barriers. A fragments loaded
//   straight from global (f32x4 pairs, 128B-coalesced per 4 lanes, L1-shared
//   across the block's 4 waves), B fragments from bf16 Wt (16B/lane,
//   L2-resident). Manual prefetch distance 1, unroll-2 ping-pong.
// ---------------------------------------------------------------------------
__device__ __forceinline__ void load_frags(const float* const pA[4],
                                           const unsigned short* const pB[4],
                                           int kk, f32x4 Af[4][2], s16x8 Bf[4]) {
    #pragma unroll
    for (int mi = 0; mi < 4; ++mi) {
        const float* p = pA[mi] + (size_t)kk * 32;
        Af[mi][0] = *(const f32x4*)p;
        Af[mi][1] = *(const f32x4*)(p + 4);
    }
    #pragma unroll
    for (int ni = 0; ni < 4; ++ni)
        Bf[ni] = *(const s16x8*)(pB[ni] + (size_t)kk * 32);
}

__device__ __forceinline__ void compute_frags(const f32x4 Af[4][2],
                                              const s16x8 Bf[4],
                                              f32x4 acc[4][4]) {
    s16x8 af[4];
    #pragma unroll
    for (int mi = 0; mi < 4; ++mi) {
        s16x8 a;
        #pragma unroll
        for (int j = 0; j < 4; ++j) {
            a[j]     = f2bf(Af[mi][0][j]);
            a[4 + j] = f2bf(Af[mi][1][j]);
        }
        af[mi] = a;
    }
    #pragma unroll
    for (int mi = 0; mi < 4; ++mi)
        #pragma unroll
        for (int ni = 0; ni < 4; ++ni)
            acc[mi][ni] = __builtin_amdgcn_mfma_f32_16x16x32_bf16(
                af[mi], Bf[ni], acc[mi][ni], 0, 0, 0);
}

__global__ __launch_bounds__(256, 2)
void gemm_e_kernel(const float* __restrict__ enc,
                   const unsigned short* __restrict__ Wt,
                   const float* __restrict__ att2,
                   const float* __restrict__ Wf,
                   float* __restrict__ e_part) {
    __shared__ float e_sm[64];

    const int t    = threadIdx.x;
    const int lane = t & 63;
    const int w    = t >> 6;              // wave 0..3
    const int aBlk  = blockIdx.x;         // 0..1 (fastest: twin tiles share A in L2)
    const int mBase = blockIdx.y * 64;    // 392 tiles
    const int aBase = aBlk * 256;

    const int r = lane & 15, q = lane >> 4;

    // Per-lane fragment base pointers (k-invariant part)
    const float* pA[4];
    #pragma unroll
    for (int mi = 0; mi < 4; ++mi)
        pA[mi] = enc + (size_t)(mBase + mi * 16 + r) * ENC + q * 8;
    const unsigned short* pB[4];
    #pragma unroll
    for (int ni = 0; ni < 4; ++ni)
        pB[ni] = Wt + (size_t)(aBase + w * 64 + ni * 16 + r) * ENC + q * 8;

    f32x4 acc[4][4] = {};
    f32x4 A0[4][2], A1[4][2];
    s16x8 B0[4], B1[4];

    load_frags(pA, pB, 0, A0, B0);
    #pragma unroll 1
    for (int ks = 0; ks < ENC / 32; ks += 2) {
        load_frags(pA, pB, ks + 1, A1, B1);
        compute_frags(A0, B0, acc);
        int kn = (ks + 2 < ENC / 32) ? ks + 2 : (ENC / 32 - 1); // clamp: last load redundant
        load_frags(pA, pB, kn, A0, B0);
        compute_frags(A1, B1, acc);
    }

    // --- epilogue: e contribution = sum_a relu(att1 + att2) * Wf ---
    if (t < 64) e_sm[t] = 0.f;
    __syncthreads();

    float wfv[4];
    #pragma unroll
    for (int ni = 0; ni < 4; ++ni)
        wfv[ni] = Wf[aBase + w * 64 + ni * 16 + r];

    #pragma unroll
    for (int mi = 0; mi < 4; ++mi) {
        #pragma unroll
        for (int reg = 0; reg < 4; ++reg) {
            int lrow = mi * 16 + q * 4 + reg;       // C/D: row=(lane>>4)*4+reg
            int gm = mBase + lrow;
            int b = gm / NN;
            const float* a2 = att2 + b * ATT + aBase + w * 64;
            float rs = 0.f;
            #pragma unroll
            for (int ni = 0; ni < 4; ++ni) {
                float v = acc[mi][ni][reg] + a2[ni * 16 + r];  // col = lane&15
                rs += fmaxf(v, 0.f) * wfv[ni];
            }
            atomicAdd(&e_sm[lrow], rs);
        }
    }
    __syncthreads();
    if (t < 64)
        e_part[(size_t)aBlk * MM + mBase + t] = e_sm[t];
}

// ---------------------------------------------------------------------------
// k2: softmax over N per batch, then awe[b][c] = sum_n enc[b][n][c]*alpha[n]
// ---------------------------------------------------------------------------
__global__ void softmax_awe_kernel(const float* __restrict__ enc,
                                   const float* __restrict__ e_part,
                                   const float* __restrict__ b_full,
                                   float* __restrict__ out) {
    const int b = blockIdx.x;       // 128
    const int chunk = blockIdx.y;   // 8
    const int t = threadIdx.x;      // 256
    __shared__ float sm[256];
    __shared__ float alpha_sm[NN];

    float v = -3.0e38f;
    if (t < NN) {
        int gm = b * NN + t;
        v = e_part[gm] + e_part[MM + gm] + b_full[0];
    }
    sm[t] = v;
    __syncthreads();
    for (int s = 128; s > 0; s >>= 1) {
        if (t < s) sm[t] = fmaxf(sm[t], sm[t + s]);
        __syncthreads();
    }
    float mx = sm[0];
    __syncthreads();
    float ex = (t < NN) ? __expf(v - mx) : 0.f;
    sm[t] = ex;
    __syncthreads();
    for (int s = 128; s > 0; s >>= 1) {
        if (t < s) sm[t] += sm[t + s];
        __syncthreads();
    }
    float inv = 1.0f / sm[0];
    if (t < NN) alpha_sm[t] = ex * inv;
    __syncthreads();

    if (chunk == 0 && t < NN)
        out[BB * ENC + b * NN + t] = ex * inv;   // alpha output

    const int col = chunk * 256 + t;
    const float* ep = enc + (size_t)b * NN * ENC + col;
    float acc = 0.f;
    #pragma unroll 4
    for (int n = 0; n < NN; n += 4) {
        acc += ep[(size_t)n * ENC]       * alpha_sm[n]
             + ep[(size_t)(n + 1) * ENC] * alpha_sm[n + 1]
             + ep[(size_t)(n + 2) * ENC] * alpha_sm[n + 2]
             + ep[(size_t)(n + 3) * ENC] * alpha_sm[n + 3];
    }
    out[b * ENC + col] = acc;
}

// ---------------------------------------------------------------------------
extern "C" void kernel_launch(void* const* d_in, const int* in_sizes, int n_in,
                              void* d_out, int out_size, void* d_ws, size_t ws_size,
                              hipStream_t stream) {
    const float* enc    = (const float*)d_in[0];   // [128,196,2048]
    const float* dec    = (const float*)d_in[1];   // [128,512]
    const float* W_enc  = (const float*)d_in[2];   // [2048,512]
    const float* b_enc  = (const float*)d_in[3];   // [512]
    const float* W_dec  = (const float*)d_in[4];   // [512,512]
    const float* b_dec  = (const float*)d_in[5];   // [512]
    const float* W_full = (const float*)d_in[6];   // [512]
    const float* b_full = (const float*)d_in[7];   // [1]
    float* out = (float*)d_out;                    // [128*2048 awe | 128*196 alpha]

    // workspace layout
    char* ws = (char*)d_ws;
    unsigned short* Wt = (unsigned short*)ws;                       // 2 MB
    float* att2   = (float*)(ws + (size_t)ENC * ATT * 2);           // 256 KB
    float* e_part = (float*)(ws + (size_t)ENC * ATT * 2 + BB * ATT * 4); // 2*25088*4

    transpose_convert_kernel<<<dim3(ATT / 32, ENC / 32), 256, 0, stream>>>(W_enc, Wt);
    att2_kernel<<<dim3(BB, 8), 256, 0, stream>>>(dec, W_dec, b_dec, b_enc, att2);
    gemm_e_kernel<<<dim3(2, MM / 64), 256, 0, stream>>>(enc, Wt, att2, W_full, e_part);
    softmax_awe_kernel<<<dim3(BB, 8), 256, 0, stream>>>(enc, e_part, b_full, out);
}

// Round 3
// 472.941 us; speedup vs baseline: 1.3148x; 1.3148x over previous
//
#include <hip/hip_runtime.h>
#include <hip/hip_bf16.h>

// Problem constants
#define BB   128
#define NN   196
#define MM   (BB*NN)      // 25088
#define ENC  2048
#define ATT  512
#define DEC  512
#define BK   32
#define KSTEPS (ENC/BK)   // 64

using f32x4 = __attribute__((ext_vector_type(4))) float;
using s16x8 = __attribute__((ext_vector_type(8))) short;

__device__ __forceinline__ short f2bf(float f) {
    union { __hip_bfloat16 h; short s; } u;
    u.h = __float2bfloat16(f);
    return u.s;
}

// ---------------------------------------------------------------------------
// k0a: transpose+convert W_enc [2048][512] f32 -> Wt [512][2048] bf16
// ---------------------------------------------------------------------------
__global__ void transpose_convert_kernel(const float* __restrict__ W,
                                         unsigned short* __restrict__ Wt) {
    __shared__ float tile[32][33];
    const int a0 = blockIdx.x * 32;
    const int k0 = blockIdx.y * 32;
    const int tx = threadIdx.x & 31, ty = threadIdx.x >> 5;
    #pragma unroll
    for (int i = 0; i < 32; i += 8)
        tile[ty + i][tx] = W[(size_t)(k0 + ty + i) * ATT + a0 + tx];
    __syncthreads();
    #pragma unroll
    for (int i = 0; i < 32; i += 8) {
        union { __hip_bfloat16 h; unsigned short u; } v;
        v.h = __float2bfloat16(tile[tx][ty + i]);
        Wt[(size_t)(a0 + ty + i) * ENC + k0 + tx] = v.u;
    }
}

// ---------------------------------------------------------------------------
// k0b: att2[b][a] = dec[b] @ W_dec[:,a] + b_dec[a] + b_enc[a]
// ---------------------------------------------------------------------------
__global__ void att2_kernel(const float* __restrict__ dec,
                            const float* __restrict__ Wd,
                            const float* __restrict__ bd,
                            const float* __restrict__ benc,
                            float* __restrict__ att2) {
    const int b  = blockIdx.x;
    const int c0 = blockIdx.y * 64;
    const int t  = threadIdx.x;
    const int cl = t & 63, kg = t >> 6;
    __shared__ float sdec[DEC];
    __shared__ float red[4][64];
    sdec[t]       = dec[b * DEC + t];
    sdec[t + 256] = dec[b * DEC + t + 256];
    __syncthreads();
    float acc = 0.f;
    const float* wp = Wd + c0 + cl;
    #pragma unroll 8
    for (int k = kg * 128; k < kg * 128 + 128; ++k)
        acc += sdec[k] * wp[(size_t)k * ATT];
    red[kg][cl] = acc;
    __syncthreads();
    if (t < 64) {
        float s = red[0][t] + red[1][t] + red[2][t] + red[3][t];
        att2[b * ATT + c0 + t] = s + bd[c0 + t] + benc[c0 + t];
    }
}

// ---------------------------------------------------------------------------
// k1: fused GEMM + bias + relu + dot(W_full) -> e_part[2][MM]
//   LDS double-buffer, ONE barrier per k-step. Prefetch (A: global->reg,
//   B: global_load_lds async) issued BEFORE compute so the barrier's
//   vmcnt(0) drain lands after ~400cyc of MFMA/ds_read latency cover.
//   A converted f32->bf16 in-register during staging (4 frag reads/step).
// ---------------------------------------------------------------------------
__global__ __launch_bounds__(256, 3)
void gemm_e_kernel(const float* __restrict__ enc,
                   const unsigned short* __restrict__ Wt,
                   const float* __restrict__ att2,
                   const float* __restrict__ Wf,
                   float* __restrict__ e_part) {
    __shared__ unsigned short sA[2][64 * 40];   // bf16, 80B row stride (cf-free reads)
    __shared__ unsigned short sB[2][256 * 32];  // bf16, 64B rows, XOR-swizzled chunks
    __shared__ float e_sm[64];

    const int t    = threadIdx.x;
    const int lane = t & 63;
    const int w    = t >> 6;
    const int aBlk  = blockIdx.x;         // 0..1
    const int mBase = blockIdx.y * 64;    // 392 tiles
    const int aBase = aBlk * 256;
    const int r = lane & 15, q = lane >> 4;

    // A staging map: thread -> (row = t>>2, 8 consecutive k at (t&3)*8)
    const int arow = t >> 2;
    const int akc  = (t & 3) * 8;
    const float* gA = enc + (size_t)(mBase + arow) * ENC + akc;
    const int wAoff = arow * 40 + akc;          // ushort offset into sA[buf]

    // B staging map: 4 x 16B per thread, chunk XOR-swizzled within 64B rows
    const unsigned short* gB[4];
    #pragma unroll
    for (int i = 0; i < 4; ++i) {
        int s = i * 256 + t;
        int brow = s >> 2;
        int ck = (s & 3) ^ ((brow >> 1) & 3);
        gB[i] = Wt + (size_t)(aBase + brow) * ENC + ck * 8;
    }

    // fragment read offsets (ushort units), k-invariant
    int offA[4];
    #pragma unroll
    for (int mi = 0; mi < 4; ++mi)
        offA[mi] = (mi * 16 + r) * 40 + q * 8;
    int offB[4];
    #pragma unroll
    for (int ni = 0; ni < 4; ++ni) {
        int col = w * 64 + ni * 16 + r;
        offB[ni] = col * 32 + (q ^ ((col >> 1) & 3)) * 8;
    }

    f32x4 acc[4][4] = {};

    auto issueB = [&](int ks, int buf) {
        #pragma unroll
        for (int i = 0; i < 4; ++i)
            __builtin_amdgcn_global_load_lds(
                (const __attribute__((address_space(1))) void*)(gB[i] + (size_t)ks * BK),
                (__attribute__((address_space(3))) void*)(&sB[buf][0] + (i * 256 + w * 64) * 8),
                16, 0, 0);
    };
    auto storeA = [&](int buf, f32x4 x0, f32x4 x1) {
        s16x8 v;
        #pragma unroll
        for (int j = 0; j < 4; ++j) { v[j] = f2bf(x0[j]); v[4 + j] = f2bf(x1[j]); }
        *(s16x8*)(&sA[buf][0] + wAoff) = v;
    };
    auto compute = [&](int buf) {
        s16x8 af[4], bf[4];
        #pragma unroll
        for (int mi = 0; mi < 4; ++mi)
            af[mi] = *(const s16x8*)(&sA[buf][0] + offA[mi]);
        #pragma unroll
        for (int ni = 0; ni < 4; ++ni)
            bf[ni] = *(const s16x8*)(&sB[buf][0] + offB[ni]);
        #pragma unroll
        for (int mi = 0; mi < 4; ++mi)
            #pragma unroll
            for (int ni = 0; ni < 4; ++ni)
                acc[mi][ni] = __builtin_amdgcn_mfma_f32_16x16x32_bf16(
                    af[mi], bf[ni], acc[mi][ni], 0, 0, 0);
    };

    // --- pipelined K-loop ---
    f32x4 a0, a1;
    {
        const float* p = gA;
        a0 = *(const f32x4*)p; a1 = *(const f32x4*)(p + 4);
    }
    issueB(0, 0);
    storeA(0, a0, a1);
    __syncthreads();

    #pragma unroll 1
    for (int ks = 1; ks < KSTEPS; ++ks) {
        const float* p = gA + (size_t)ks * BK;
        a0 = *(const f32x4*)p; a1 = *(const f32x4*)(p + 4);  // async, used post-compute
        issueB(ks, ks & 1);                                   // async into other buf
        compute((ks - 1) & 1);
        storeA(ks & 1, a0, a1);
        __syncthreads();
    }
    compute((KSTEPS - 1) & 1);

    // --- epilogue: e contribution = sum_a relu(att1 + att2) * Wf ---
    if (t < 64) e_sm[t] = 0.f;
    __syncthreads();

    float wfv[4];
    #pragma unroll
    for (int ni = 0; ni < 4; ++ni)
        wfv[ni] = Wf[aBase + w * 64 + ni * 16 + r];

    #pragma unroll
    for (int mi = 0; mi < 4; ++mi) {
        #pragma unroll
        for (int reg = 0; reg < 4; ++reg) {
            int lrow = mi * 16 + q * 4 + reg;       // C/D: row=(lane>>4)*4+reg
            int gm = mBase + lrow;
            int b = gm / NN;
            const float* a2 = att2 + b * ATT + aBase + w * 64;
            float rs = 0.f;
            #pragma unroll
            for (int ni = 0; ni < 4; ++ni) {
                float v = acc[mi][ni][reg] + a2[ni * 16 + r];  // col = lane&15
                rs += fmaxf(v, 0.f) * wfv[ni];
            }
            atomicAdd(&e_sm[lrow], rs);
        }
    }
    __syncthreads();
    if (t < 64)
        e_part[(size_t)aBlk * MM + mBase + t] = e_sm[t];
}

// ---------------------------------------------------------------------------
// k2a: softmax over N per batch -> alpha (out tail + ws copy)
// ---------------------------------------------------------------------------
__global__ void softmax_kernel(const float* __restrict__ e_part,
                               const float* __restrict__ b_full,
                               float* __restrict__ out,
                               float* __restrict__ alpha_ws) {
    const int b = blockIdx.x;
    const int t = threadIdx.x;      // 256
    __shared__ float sm[256];

    float v = -3.0e38f;
    if (t < NN) {
        int gm = b * NN + t;
        v = e_part[gm] + e_part[MM + gm] + b_full[0];
    }
    sm[t] = v;
    __syncthreads();
    for (int s = 128; s > 0; s >>= 1) {
        if (t < s) sm[t] = fmaxf(sm[t], sm[t + s]);
        __syncthreads();
    }
    float mx = sm[0];
    __syncthreads();
    float ex = (t < NN) ? __expf(v - mx) : 0.f;
    sm[t] = ex;
    __syncthreads();
    for (int s = 128; s > 0; s >>= 1) {
        if (t < s) sm[t] += sm[t + s];
        __syncthreads();
    }
    float inv = 1.0f / sm[0];
    if (t < NN) {
        float a = ex * inv;
        out[BB * ENC + b * NN + t] = a;
        alpha_ws[b * NN + t] = a;
    }
}

// ---------------------------------------------------------------------------
// k2b: awe[b][c] = sum_n enc[b][n][c] * alpha[b][n]
//   (128,8) x 64 threads; each lane 4 cols (f32x4); 4 independent acc chains.
// ---------------------------------------------------------------------------
__global__ __launch_bounds__(64)
void awe_kernel(const float* __restrict__ enc,
                const float* __restrict__ alpha_ws,
                float* __restrict__ out) {
    const int b = blockIdx.x, chunk = blockIdx.y;
    const int l = threadIdx.x;      // 64
    __shared__ float al[NN];
    for (int n = l; n < NN; n += 64) al[n] = alpha_ws[b * NN + n];
    __syncthreads();

    const float* ep = enc + (size_t)b * NN * ENC + chunk * 256 + l * 4;
    f32x4 acc0 = {}, acc1 = {}, acc2 = {}, acc3 = {};
    #pragma unroll 2
    for (int n = 0; n < NN; n += 4) {   // 196 = 4*49 exact
        f32x4 v0 = *(const f32x4*)(ep + (size_t)(n + 0) * ENC);
        f32x4 v1 = *(const f32x4*)(ep + (size_t)(n + 1) * ENC);
        f32x4 v2 = *(const f32x4*)(ep + (size_t)(n + 2) * ENC);
        f32x4 v3 = *(const f32x4*)(ep + (size_t)(n + 3) * ENC);
        acc0 += v0 * al[n];
        acc1 += v1 * al[n + 1];
        acc2 += v2 * al[n + 2];
        acc3 += v3 * al[n + 3];
    }
    f32x4 s = (acc0 + acc1) + (acc2 + acc3);
    *(f32x4*)(out + (size_t)b * ENC + chunk * 256 + l * 4) = s;
}

// ---------------------------------------------------------------------------
extern "C" void kernel_launch(void* const* d_in, const int* in_sizes, int n_in,
                              void* d_out, int out_size, void* d_ws, size_t ws_size,
                              hipStream_t stream) {
    const float* enc    = (const float*)d_in[0];
    const float* dec    = (const float*)d_in[1];
    const float* W_enc  = (const float*)d_in[2];
    const float* b_enc  = (const float*)d_in[3];
    const float* W_dec  = (const float*)d_in[4];
    const float* b_dec  = (const float*)d_in[5];
    const float* W_full = (const float*)d_in[6];
    const float* b_full = (const float*)d_in[7];
    float* out = (float*)d_out;   // [128*2048 awe | 128*196 alpha]

    char* ws = (char*)d_ws;
    unsigned short* Wt = (unsigned short*)ws;                              // 2 MB
    float* att2     = (float*)(ws + (size_t)ENC * ATT * 2);                // 256 KB
    float* e_part   = (float*)(ws + (size_t)ENC * ATT * 2 + BB * ATT * 4); // 200 KB
    float* alpha_ws = (float*)(ws + (size_t)ENC * ATT * 2 + BB * ATT * 4
                               + (size_t)2 * MM * 4);                      // 100 KB

    transpose_convert_kernel<<<dim3(ATT / 32, ENC / 32), 256, 0, stream>>>(W_enc, Wt);
    att2_kernel<<<dim3(BB, 8), 256, 0, stream>>>(dec, W_dec, b_dec, b_enc, att2);
    gemm_e_kernel<<<dim3(2, MM / 64), 256, 0, stream>>>(enc, Wt, att2, W_full, e_part);
    softmax_kernel<<<BB, 256, 0, stream>>>(e_part, b_full, out, alpha_ws);
    awe_kernel<<<dim3(BB, 8), 64, 0, stream>>>(enc, alpha_ws, out);
}

// Round 4
// 457.186 us; speedup vs baseline: 1.3601x; 1.0345x over previous
//
#include <hip/hip_runtime.h>
#include <hip/hip_bf16.h>

// Problem constants
#define BB   128
#define NN   196
#define MM   (BB*NN)      // 25088
#define ENC  2048
#define ATT  512
#define DEC  512
#define BK   32
#define KSTEPS (ENC/BK)   // 64

using f32x4 = __attribute__((ext_vector_type(4))) float;
using s16x8 = __attribute__((ext_vector_type(8))) short;

__device__ __forceinline__ short f2bf(float f) {
    union { __hip_bfloat16 h; short s; } u;
    u.h = __float2bfloat16(f);
    return u.s;
}

// ---------------------------------------------------------------------------
// k0a: transpose+convert W_enc [2048][512] f32 -> Wt [512][2048] bf16
// ---------------------------------------------------------------------------
__global__ void transpose_convert_kernel(const float* __restrict__ W,
                                         unsigned short* __restrict__ Wt) {
    __shared__ float tile[32][33];
    const int a0 = blockIdx.x * 32;
    const int k0 = blockIdx.y * 32;
    const int tx = threadIdx.x & 31, ty = threadIdx.x >> 5;
    #pragma unroll
    for (int i = 0; i < 32; i += 8)
        tile[ty + i][tx] = W[(size_t)(k0 + ty + i) * ATT + a0 + tx];
    __syncthreads();
    #pragma unroll
    for (int i = 0; i < 32; i += 8) {
        union { __hip_bfloat16 h; unsigned short u; } v;
        v.h = __float2bfloat16(tile[tx][ty + i]);
        Wt[(size_t)(a0 + ty + i) * ENC + k0 + tx] = v.u;
    }
}

// ---------------------------------------------------------------------------
// k0b: att2[b][a] = dec[b] @ W_dec[:,a] + b_dec[a] + b_enc[a]
// ---------------------------------------------------------------------------
__global__ void att2_kernel(const float* __restrict__ dec,
                            const float* __restrict__ Wd,
                            const float* __restrict__ bd,
                            const float* __restrict__ benc,
                            float* __restrict__ att2) {
    const int b  = blockIdx.x;
    const int c0 = blockIdx.y * 64;
    const int t  = threadIdx.x;
    const int cl = t & 63, kg = t >> 6;
    __shared__ float sdec[DEC];
    __shared__ float red[4][64];
    sdec[t]       = dec[b * DEC + t];
    sdec[t + 256] = dec[b * DEC + t + 256];
    __syncthreads();
    float acc = 0.f;
    const float* wp = Wd + c0 + cl;
    #pragma unroll 8
    for (int k = kg * 128; k < kg * 128 + 128; ++k)
        acc += sdec[k] * wp[(size_t)k * ATT];
    red[kg][cl] = acc;
    __syncthreads();
    if (t < 64) {
        float s = red[0][t] + red[1][t] + red[2][t] + red[3][t];
        att2[b * ATT + c0 + t] = s + bd[c0 + t] + benc[c0 + t];
    }
}

// ---------------------------------------------------------------------------
// k1: fused GEMM + bias + relu + dot(W_full) -> e_part[4][MM]
//   Concurrency-first redesign: tile 64m x 128a, grid 1568 blocks (6/CU),
//   LDS 16.6 KB single-buffered, 2 barriers/step (m97 structure).
//   A fp32 + B bf16 both staged via global_load_lds(16B) with XOR chunk
//   swizzles giving 2-way (free) LDS frag-read conflicts.
//   Wave tile 64m x 32a: 4 A-frags x 2 B-frags = 8 MFMA/step.
// ---------------------------------------------------------------------------
__global__ __launch_bounds__(256, 5)
void gemm_e_kernel(const float* __restrict__ enc,
                   const unsigned short* __restrict__ Wt,
                   const float* __restrict__ att2,
                   const float* __restrict__ Wf,
                   float* __restrict__ e_part) {
    __shared__ float sA[64 * 32];            // 8 KB, chunk-swizzled
    __shared__ unsigned short sB[128 * 32];  // 8 KB, chunk-swizzled
    __shared__ float e_sm[64];

    const int t    = threadIdx.x;
    const int lane = t & 63;
    const int w    = t >> 6;
    const int aBlk  = blockIdx.x;         // 0..3
    const int mBase = blockIdx.y * 64;    // 392 tiles
    const int aBase = aBlk * 128;
    const int r = lane & 15, q = lane >> 4;

    // --- A staging map: inst i: s = i*256+t -> row=s>>3, ckpos=s&7,
    //     fetch global chunk g = ckpos ^ (row&7). LDS layout linear in s.
    const float* gA[2];
    #pragma unroll
    for (int i = 0; i < 2; ++i) {
        int s = i * 256 + t;
        int row = s >> 3, ck = s & 7;
        int g = ck ^ (row & 7);
        gA[i] = enc + (size_t)(mBase + row) * ENC + g * 4;
    }
    // --- B staging map: inst i: s = i*256+t -> row=s>>2, ckpos=s&3,
    //     fetch chunk g = ckpos ^ F(row), F(row)=(row&3)^((row>>2)&3)
    const unsigned short* gB[2];
    #pragma unroll
    for (int i = 0; i < 2; ++i) {
        int s = i * 256 + t;
        int row = s >> 2, ck = s & 3;
        int g = ck ^ ((row & 3) ^ ((row >> 2) & 3));
        gB[i] = Wt + (size_t)(aBase + row) * ENC + g * 8;
    }

    // --- fragment read byte offsets (k-invariant) ---
    int offA[4][2];
    #pragma unroll
    for (int mi = 0; mi < 4; ++mi) {
        int row = mi * 16 + r;
        offA[mi][0] = row * 128 + ((2 * q)     ^ (row & 7)) * 16;
        offA[mi][1] = row * 128 + ((2 * q + 1) ^ (row & 7)) * 16;
    }
    int offB[2];
    #pragma unroll
    for (int ni = 0; ni < 2; ++ni) {
        int col = w * 32 + ni * 16 + r;
        offB[ni] = col * 64 + (q ^ ((col & 3) ^ ((col >> 2) & 3))) * 16;
    }

    f32x4 acc[4][2] = {};

    #pragma unroll 1
    for (int ks = 0; ks < KSTEPS; ++ks) {
        #pragma unroll
        for (int i = 0; i < 2; ++i)
            __builtin_amdgcn_global_load_lds(
                (const __attribute__((address_space(1))) void*)(gA[i] + (size_t)ks * BK),
                (__attribute__((address_space(3))) void*)((char*)sA + (i * 256 + w * 64) * 16),
                16, 0, 0);
        #pragma unroll
        for (int i = 0; i < 2; ++i)
            __builtin_amdgcn_global_load_lds(
                (const __attribute__((address_space(1))) void*)(gB[i] + (size_t)ks * BK),
                (__attribute__((address_space(3))) void*)((char*)sB + (i * 256 + w * 64) * 16),
                16, 0, 0);
        __syncthreads();

        s16x8 af[4], bf[2];
        #pragma unroll
        for (int mi = 0; mi < 4; ++mi) {
            f32x4 f0 = *(const f32x4*)((const char*)sA + offA[mi][0]);
            f32x4 f1 = *(const f32x4*)((const char*)sA + offA[mi][1]);
            s16x8 a;
            #pragma unroll
            for (int j = 0; j < 4; ++j) { a[j] = f2bf(f0[j]); a[4 + j] = f2bf(f1[j]); }
            af[mi] = a;
        }
        #pragma unroll
        for (int ni = 0; ni < 2; ++ni)
            bf[ni] = *(const s16x8*)((const char*)sB + offB[ni]);

        #pragma unroll
        for (int mi = 0; mi < 4; ++mi)
            #pragma unroll
            for (int ni = 0; ni < 2; ++ni)
                acc[mi][ni] = __builtin_amdgcn_mfma_f32_16x16x32_bf16(
                    af[mi], bf[ni], acc[mi][ni], 0, 0, 0);
        __syncthreads();
    }

    // --- epilogue: e contribution = sum_a relu(att1 + att2) * Wf ---
    if (t < 64) e_sm[t] = 0.f;
    __syncthreads();

    float wfv[2];
    #pragma unroll
    for (int ni = 0; ni < 2; ++ni)
        wfv[ni] = Wf[aBase + w * 32 + ni * 16 + r];

    #pragma unroll
    for (int mi = 0; mi < 4; ++mi) {
        #pragma unroll
        for (int reg = 0; reg < 4; ++reg) {
            int lrow = mi * 16 + q * 4 + reg;       // C/D: row=(lane>>4)*4+reg
            int gm = mBase + lrow;
            int b = gm / NN;
            const float* a2 = att2 + b * ATT + aBase + w * 32;
            float rs = 0.f;
            #pragma unroll
            for (int ni = 0; ni < 2; ++ni) {
                float v = acc[mi][ni][reg] + a2[ni * 16 + r];  // col = lane&15
                rs += fmaxf(v, 0.f) * wfv[ni];
            }
            // reduce over the 16 r-lanes (low 4 lane bits), then one atomic
            rs += __shfl_xor(rs, 1);
            rs += __shfl_xor(rs, 2);
            rs += __shfl_xor(rs, 4);
            rs += __shfl_xor(rs, 8);
            if (r == 0) atomicAdd(&e_sm[lrow], rs);
        }
    }
    __syncthreads();
    if (t < 64)
        e_part[(size_t)aBlk * MM + mBase + t] = e_sm[t];
}

// ---------------------------------------------------------------------------
// k2a: softmax over N per batch -> alpha (out tail + ws copy)
// ---------------------------------------------------------------------------
__global__ void softmax_kernel(const float* __restrict__ e_part,
                               const float* __restrict__ b_full,
                               float* __restrict__ out,
                               float* __restrict__ alpha_ws) {
    const int b = blockIdx.x;
    const int t = threadIdx.x;      // 256
    __shared__ float sm[256];

    float v = -3.0e38f;
    if (t < NN) {
        int gm = b * NN + t;
        v = e_part[gm] + e_part[MM + gm] + e_part[2 * MM + gm] + e_part[3 * MM + gm]
            + b_full[0];
    }
    sm[t] = v;
    __syncthreads();
    for (int s = 128; s > 0; s >>= 1) {
        if (t < s) sm[t] = fmaxf(sm[t], sm[t + s]);
        __syncthreads();
    }
    float mx = sm[0];
    __syncthreads();
    float ex = (t < NN) ? __expf(v - mx) : 0.f;
    sm[t] = ex;
    __syncthreads();
    for (int s = 128; s > 0; s >>= 1) {
        if (t < s) sm[t] += sm[t + s];
        __syncthreads();
    }
    float inv = 1.0f / sm[0];
    if (t < NN) {
        float a = ex * inv;
        out[BB * ENC + b * NN + t] = a;
        alpha_ws[b * NN + t] = a;
    }
}

// ---------------------------------------------------------------------------
// k2b: awe[b][c] = sum_n enc[b][n][c] * alpha[b][n]
//   (128,2) x 256 threads; lane = f32x4 column group; 8 loads in flight.
// ---------------------------------------------------------------------------
__global__ __launch_bounds__(256)
void awe_kernel(const float* __restrict__ enc,
                const float* __restrict__ alpha_ws,
                float* __restrict__ out) {
    const int b = blockIdx.x, chunk = blockIdx.y;
    const int t = threadIdx.x;      // 256
    __shared__ float al[NN];
    if (t < NN) al[t] = alpha_ws[b * NN + t];
    __syncthreads();

    const float* ep = enc + (size_t)b * NN * ENC + chunk * 1024 + t * 4;
    f32x4 acc0 = {}, acc1 = {}, acc2 = {}, acc3 = {};
    #pragma unroll 2
    for (int n = 0; n < NN; n += 4) {   // 196 = 4*49 exact
        f32x4 v0 = *(const f32x4*)(ep + (size_t)(n + 0) * ENC);
        f32x4 v1 = *(const f32x4*)(ep + (size_t)(n + 1) * ENC);
        f32x4 v2 = *(const f32x4*)(ep + (size_t)(n + 2) * ENC);
        f32x4 v3 = *(const f32x4*)(ep + (size_t)(n + 3) * ENC);
        acc0 += v0 * al[n];
        acc1 += v1 * al[n + 1];
        acc2 += v2 * al[n + 2];
        acc3 += v3 * al[n + 3];
    }
    f32x4 s = (acc0 + acc1) + (acc2 + acc3);
    *(f32x4*)(out + (size_t)b * ENC + chunk * 1024 + t * 4) = s;
}

// ---------------------------------------------------------------------------
extern "C" void kernel_launch(void* const* d_in, const int* in_sizes, int n_in,
                              void* d_out, int out_size, void* d_ws, size_t ws_size,
                              hipStream_t stream) {
    const float* enc    = (const float*)d_in[0];
    const float* dec    = (const float*)d_in[1];
    const float* W_enc  = (const float*)d_in[2];
    const float* b_enc  = (const float*)d_in[3];
    const float* W_dec  = (const float*)d_in[4];
    const float* b_dec  = (const float*)d_in[5];
    const float* W_full = (const float*)d_in[6];
    const float* b_full = (const float*)d_in[7];
    float* out = (float*)d_out;   // [128*2048 awe | 128*196 alpha]

    char* ws = (char*)d_ws;
    unsigned short* Wt = (unsigned short*)ws;                              // 2 MB
    float* att2     = (float*)(ws + (size_t)ENC * ATT * 2);                // 256 KB
    float* e_part   = (float*)(ws + (size_t)ENC * ATT * 2 + BB * ATT * 4); // 4*MM*4 = 400 KB
    float* alpha_ws = (float*)(ws + (size_t)ENC * ATT * 2 + BB * ATT * 4
                               + (size_t)4 * MM * 4);                      // 100 KB

    transpose_convert_kernel<<<dim3(ATT / 32, ENC / 32), 256, 0, stream>>>(W_enc, Wt);
    att2_kernel<<<dim3(BB, 8), 256, 0, stream>>>(dec, W_dec, b_dec, b_enc, att2);
    gemm_e_kernel<<<dim3(4, MM / 64), 256, 0, stream>>>(enc, Wt, att2, W_full, e_part);
    softmax_kernel<<<BB, 256, 0, stream>>>(e_part, b_full, out, alpha_ws);
    awe_kernel<<<dim3(BB, 2), 256, 0, stream>>>(enc, alpha_ws, out);
}

// Round 5
// 445.835 us; speedup vs baseline: 1.3948x; 1.0255x over previous
//
#include <hip/hip_runtime.h>
#include <hip/hip_bf16.h>

// Problem constants
#define BB   128
#define NN   196
#define MM   (BB*NN)      // 25088
#define ENC  2048
#define ATT  512
#define DEC  512
#define BK   32
#define KSTEPS (ENC/BK)   // 64

using f32x4 = __attribute__((ext_vector_type(4))) float;
using s16x8 = __attribute__((ext_vector_type(8))) short;
using u16x4 = __attribute__((ext_vector_type(4))) unsigned short;
using u16x8 = __attribute__((ext_vector_type(8))) unsigned short;

__device__ __forceinline__ short f2bf(float f) {
    union { __hip_bfloat16 h; short s; } u;
    u.h = __float2bfloat16(f);
    return u.s;
}
__device__ __forceinline__ float bf2f(unsigned short u) {
    union { unsigned int i; float f; } v;
    v.i = ((unsigned int)u) << 16;
    return v.f;
}

// ---------------------------------------------------------------------------
// k0a: transpose+convert W_enc [2048][512] f32 -> Wt [512][2048] bf16
// ---------------------------------------------------------------------------
__global__ void transpose_convert_kernel(const float* __restrict__ W,
                                         unsigned short* __restrict__ Wt) {
    __shared__ float tile[32][33];
    const int a0 = blockIdx.x * 32;
    const int k0 = blockIdx.y * 32;
    const int tx = threadIdx.x & 31, ty = threadIdx.x >> 5;
    #pragma unroll
    for (int i = 0; i < 32; i += 8)
        tile[ty + i][tx] = W[(size_t)(k0 + ty + i) * ATT + a0 + tx];
    __syncthreads();
    #pragma unroll
    for (int i = 0; i < 32; i += 8) {
        union { __hip_bfloat16 h; unsigned short u; } v;
        v.h = __float2bfloat16(tile[tx][ty + i]);
        Wt[(size_t)(a0 + ty + i) * ENC + k0 + tx] = v.u;
    }
}

// ---------------------------------------------------------------------------
// k0c: convert encoder_out fp32 -> bf16 (row per block; 256 thr x 8 elem)
// ---------------------------------------------------------------------------
__global__ __launch_bounds__(256)
void enc_cvt_kernel(const float* __restrict__ enc,
                    unsigned short* __restrict__ encb) {
    const size_t row = blockIdx.x;
    const int t = threadIdx.x;
    const float* in = enc + row * ENC + t * 8;
    f32x4 a = *(const f32x4*)in;
    f32x4 b = *(const f32x4*)(in + 4);
    u16x8 o;
    #pragma unroll
    for (int j = 0; j < 4; ++j) {
        o[j]     = (unsigned short)f2bf(a[j]);
        o[4 + j] = (unsigned short)f2bf(b[j]);
    }
    *(u16x8*)(encb + row * ENC + t * 8) = o;
}

// ---------------------------------------------------------------------------
// k0b: att2[b][a] = dec[b] @ W_dec[:,a] + b_dec[a] + b_enc[a]
// ---------------------------------------------------------------------------
__global__ void att2_kernel(const float* __restrict__ dec,
                            const float* __restrict__ Wd,
                            const float* __restrict__ bd,
                            const float* __restrict__ benc,
                            float* __restrict__ att2) {
    const int b  = blockIdx.x;
    const int c0 = blockIdx.y * 64;
    const int t  = threadIdx.x;
    const int cl = t & 63, kg = t >> 6;
    __shared__ float sdec[DEC];
    __shared__ float red[4][64];
    sdec[t]       = dec[b * DEC + t];
    sdec[t + 256] = dec[b * DEC + t + 256];
    __syncthreads();
    float acc = 0.f;
    const float* wp = Wd + c0 + cl;
    #pragma unroll 8
    for (int k = kg * 128; k < kg * 128 + 128; ++k)
        acc += sdec[k] * wp[(size_t)k * ATT];
    red[kg][cl] = acc;
    __syncthreads();
    if (t < 64) {
        float s = red[0][t] + red[1][t] + red[2][t] + red[3][t];
        att2[b * ATT + c0 + t] = s + bd[c0 + t] + benc[c0 + t];
    }
}

// ---------------------------------------------------------------------------
// k1 MAIN: fused GEMM + bias + relu + dot(W_full) -> e_part[2][MM]
//   m97-exact step profile: all-bf16 operands, 64m x 256a tile, BK=32,
//   LDS 20.6 KB single-buffered, per thread-step 5 global_load_lds(16B),
//   per wave-step 8 ds_read_b128 + 16 MFMA. Grid (2, 392) = 784 blocks.
// ---------------------------------------------------------------------------
__global__ __launch_bounds__(256, 4)
void gemm_bf16_kernel(const unsigned short* __restrict__ encb,
                      const unsigned short* __restrict__ Wt,
                      const float* __restrict__ att2,
                      const float* __restrict__ Wf,
                      float* __restrict__ e_part) {
    __shared__ unsigned short sA[64 * 32];    // 4 KB, 64B rows
    __shared__ unsigned short sB[256 * 32];   // 16 KB, 64B rows
    __shared__ float e_sm[64];

    const int t    = threadIdx.x;
    const int lane = t & 63;
    const int w    = t >> 6;
    const int aBlk  = blockIdx.x;          // 0..1
    const int mBase = blockIdx.y * 64;     // 392 tiles
    const int aBase = aBlk * 256;
    const int r = lane & 15, q = lane >> 4;

    // staging pointers (linear LDS layout = row-major 64B rows)
    const unsigned short* gA = encb + (size_t)(mBase + (t >> 2)) * ENC + (t & 3) * 8;
    const unsigned short* gB[4];
    #pragma unroll
    for (int i = 0; i < 4; ++i) {
        int s = i * 256 + t;
        gB[i] = Wt + (size_t)(aBase + (s >> 2)) * ENC + (s & 3) * 8;
    }

    // fragment byte offsets (k-invariant)
    int offA[4];
    #pragma unroll
    for (int mi = 0; mi < 4; ++mi)
        offA[mi] = (mi * 16 + r) * 64 + q * 16;
    int offB[4];
    #pragma unroll
    for (int ni = 0; ni < 4; ++ni)
        offB[ni] = (w * 64 + ni * 16 + r) * 64 + q * 16;

    f32x4 acc[4][4] = {};

    #pragma unroll 1
    for (int ks = 0; ks < KSTEPS; ++ks) {
        __builtin_amdgcn_global_load_lds(
            (const __attribute__((address_space(1))) void*)(gA + (size_t)ks * BK),
            (__attribute__((address_space(3))) void*)((char*)sA + t * 16),
            16, 0, 0);
        #pragma unroll
        for (int i = 0; i < 4; ++i)
            __builtin_amdgcn_global_load_lds(
                (const __attribute__((address_space(1))) void*)(gB[i] + (size_t)ks * BK),
                (__attribute__((address_space(3))) void*)((char*)sB + (i * 256 + t) * 16),
                16, 0, 0);
        __syncthreads();

        s16x8 af[4], bf[4];
        #pragma unroll
        for (int mi = 0; mi < 4; ++mi)
            af[mi] = *(const s16x8*)((const char*)sA + offA[mi]);
        #pragma unroll
        for (int ni = 0; ni < 4; ++ni)
            bf[ni] = *(const s16x8*)((const char*)sB + offB[ni]);

        #pragma unroll
        for (int mi = 0; mi < 4; ++mi)
            #pragma unroll
            for (int ni = 0; ni < 4; ++ni)
                acc[mi][ni] = __builtin_amdgcn_mfma_f32_16x16x32_bf16(
                    af[mi], bf[ni], acc[mi][ni], 0, 0, 0);
        __syncthreads();
    }

    // --- epilogue: e contribution = sum_a relu(att1 + att2) * Wf ---
    if (t < 64) e_sm[t] = 0.f;
    __syncthreads();

    float wfv[4];
    #pragma unroll
    for (int ni = 0; ni < 4; ++ni)
        wfv[ni] = Wf[aBase + w * 64 + ni * 16 + r];

    #pragma unroll
    for (int mi = 0; mi < 4; ++mi) {
        #pragma unroll
        for (int reg = 0; reg < 4; ++reg) {
            int lrow = mi * 16 + q * 4 + reg;       // C/D: row=(lane>>4)*4+reg
            int gm = mBase + lrow;
            int b = gm / NN;
            const float* a2 = att2 + b * ATT + aBase + w * 64;
            float rs = 0.f;
            #pragma unroll
            for (int ni = 0; ni < 4; ++ni) {
                float v = acc[mi][ni][reg] + a2[ni * 16 + r];  // col = lane&15
                rs += fmaxf(v, 0.f) * wfv[ni];
            }
            rs += __shfl_xor(rs, 1);
            rs += __shfl_xor(rs, 2);
            rs += __shfl_xor(rs, 4);
            rs += __shfl_xor(rs, 8);
            if (r == 0) atomicAdd(&e_sm[lrow], rs);
        }
    }
    __syncthreads();
    if (t < 64)
        e_part[(size_t)aBlk * MM + mBase + t] = e_sm[t];
}

// ---------------------------------------------------------------------------
// k1 FALLBACK (R4): 64m x 128a fp32-A gemm -> e_part[4][MM]
// ---------------------------------------------------------------------------
__global__ __launch_bounds__(256, 5)
void gemm_e_kernel(const float* __restrict__ enc,
                   const unsigned short* __restrict__ Wt,
                   const float* __restrict__ att2,
                   const float* __restrict__ Wf,
                   float* __restrict__ e_part) {
    __shared__ float sA[64 * 32];
    __shared__ unsigned short sB[128 * 32];
    __shared__ float e_sm[64];

    const int t    = threadIdx.x;
    const int lane = t & 63;
    const int w    = t >> 6;
    const int aBlk  = blockIdx.x;
    const int mBase = blockIdx.y * 64;
    const int aBase = aBlk * 128;
    const int r = lane & 15, q = lane >> 4;

    const float* gA[2];
    #pragma unroll
    for (int i = 0; i < 2; ++i) {
        int s = i * 256 + t;
        int row = s >> 3, ck = s & 7;
        int g = ck ^ (row & 7);
        gA[i] = enc + (size_t)(mBase + row) * ENC + g * 4;
    }
    const unsigned short* gB[2];
    #pragma unroll
    for (int i = 0; i < 2; ++i) {
        int s = i * 256 + t;
        int row = s >> 2, ck = s & 3;
        int g = ck ^ ((row & 3) ^ ((row >> 2) & 3));
        gB[i] = Wt + (size_t)(aBase + row) * ENC + g * 8;
    }

    int offA[4][2];
    #pragma unroll
    for (int mi = 0; mi < 4; ++mi) {
        int row = mi * 16 + r;
        offA[mi][0] = row * 128 + ((2 * q)     ^ (row & 7)) * 16;
        offA[mi][1] = row * 128 + ((2 * q + 1) ^ (row & 7)) * 16;
    }
    int offB[2];
    #pragma unroll
    for (int ni = 0; ni < 2; ++ni) {
        int col = w * 32 + ni * 16 + r;
        offB[ni] = col * 64 + (q ^ ((col & 3) ^ ((col >> 2) & 3))) * 16;
    }

    f32x4 acc[4][2] = {};

    #pragma unroll 1
    for (int ks = 0; ks < KSTEPS; ++ks) {
        #pragma unroll
        for (int i = 0; i < 2; ++i)
            __builtin_amdgcn_global_load_lds(
                (const __attribute__((address_space(1))) void*)(gA[i] + (size_t)ks * BK),
                (__attribute__((address_space(3))) void*)((char*)sA + (i * 256 + w * 64) * 16),
                16, 0, 0);
        #pragma unroll
        for (int i = 0; i < 2; ++i)
            __builtin_amdgcn_global_load_lds(
                (const __attribute__((address_space(1))) void*)(gB[i] + (size_t)ks * BK),
                (__attribute__((address_space(3))) void*)((char*)sB + (i * 256 + w * 64) * 16),
                16, 0, 0);
        __syncthreads();

        s16x8 af[4], bf[2];
        #pragma unroll
        for (int mi = 0; mi < 4; ++mi) {
            f32x4 f0 = *(const f32x4*)((const char*)sA + offA[mi][0]);
            f32x4 f1 = *(const f32x4*)((const char*)sA + offA[mi][1]);
            s16x8 a;
            #pragma unroll
            for (int j = 0; j < 4; ++j) { a[j] = f2bf(f0[j]); a[4 + j] = f2bf(f1[j]); }
            af[mi] = a;
        }
        #pragma unroll
        for (int ni = 0; ni < 2; ++ni)
            bf[ni] = *(const s16x8*)((const char*)sB + offB[ni]);

        #pragma unroll
        for (int mi = 0; mi < 4; ++mi)
            #pragma unroll
            for (int ni = 0; ni < 2; ++ni)
                acc[mi][ni] = __builtin_amdgcn_mfma_f32_16x16x32_bf16(
                    af[mi], bf[ni], acc[mi][ni], 0, 0, 0);
        __syncthreads();
    }

    if (t < 64) e_sm[t] = 0.f;
    __syncthreads();

    float wfv[2];
    #pragma unroll
    for (int ni = 0; ni < 2; ++ni)
        wfv[ni] = Wf[aBase + w * 32 + ni * 16 + r];

    #pragma unroll
    for (int mi = 0; mi < 4; ++mi) {
        #pragma unroll
        for (int reg = 0; reg < 4; ++reg) {
            int lrow = mi * 16 + q * 4 + reg;
            int gm = mBase + lrow;
            int b = gm / NN;
            const float* a2 = att2 + b * ATT + aBase + w * 32;
            float rs = 0.f;
            #pragma unroll
            for (int ni = 0; ni < 2; ++ni) {
                float v = acc[mi][ni][reg] + a2[ni * 16 + r];
                rs += fmaxf(v, 0.f) * wfv[ni];
            }
            rs += __shfl_xor(rs, 1);
            rs += __shfl_xor(rs, 2);
            rs += __shfl_xor(rs, 4);
            rs += __shfl_xor(rs, 8);
            if (r == 0) atomicAdd(&e_sm[lrow], rs);
        }
    }
    __syncthreads();
    if (t < 64)
        e_part[(size_t)aBlk * MM + mBase + t] = e_sm[t];
}

// ---------------------------------------------------------------------------
// k2a: softmax over N per batch -> alpha (out tail + ws copy); nparts variable
// ---------------------------------------------------------------------------
__global__ void softmax_kernel(const float* __restrict__ e_part,
                               const float* __restrict__ b_full,
                               float* __restrict__ out,
                               float* __restrict__ alpha_ws,
                               int nparts) {
    const int b = blockIdx.x;
    const int t = threadIdx.x;      // 256
    __shared__ float sm[256];

    float v = -3.0e38f;
    if (t < NN) {
        int gm = b * NN + t;
        float s = b_full[0];
        for (int p = 0; p < nparts; ++p) s += e_part[(size_t)p * MM + gm];
        v = s;
    }
    sm[t] = v;
    __syncthreads();
    for (int s = 128; s > 0; s >>= 1) {
        if (t < s) sm[t] = fmaxf(sm[t], sm[t + s]);
        __syncthreads();
    }
    float mx = sm[0];
    __syncthreads();
    float ex = (t < NN) ? __expf(v - mx) : 0.f;
    sm[t] = ex;
    __syncthreads();
    for (int s = 128; s > 0; s >>= 1) {
        if (t < s) sm[t] += sm[t + s];
        __syncthreads();
    }
    float inv = 1.0f / sm[0];
    if (t < NN) {
        float a = ex * inv;
        out[BB * ENC + b * NN + t] = a;
        alpha_ws[b * NN + t] = a;
    }
}

// ---------------------------------------------------------------------------
// k2b MAIN: awe from bf16 encoder copy. (128,2) x 256; lane = 4 cols (8B loads).
// ---------------------------------------------------------------------------
__global__ __launch_bounds__(256)
void awe_bf16_kernel(const unsigned short* __restrict__ encb,
                     const float* __restrict__ alpha_ws,
                     float* __restrict__ out) {
    const int b = blockIdx.x, chunk = blockIdx.y;
    const int t = threadIdx.x;
    __shared__ float al[NN];
    if (t < NN) al[t] = alpha_ws[b * NN + t];
    __syncthreads();

    const unsigned short* ep = encb + (size_t)b * NN * ENC + chunk * 1024 + t * 4;
    f32x4 acc0 = {}, acc1 = {}, acc2 = {}, acc3 = {};
    #pragma unroll 2
    for (int n = 0; n < NN; n += 4) {   // 196 = 4*49 exact
        u16x4 v0 = *(const u16x4*)(ep + (size_t)(n + 0) * ENC);
        u16x4 v1 = *(const u16x4*)(ep + (size_t)(n + 1) * ENC);
        u16x4 v2 = *(const u16x4*)(ep + (size_t)(n + 2) * ENC);
        u16x4 v3 = *(const u16x4*)(ep + (size_t)(n + 3) * ENC);
        #pragma unroll
        for (int j = 0; j < 4; ++j) {
            acc0[j] += bf2f(v0[j]) * al[n];
            acc1[j] += bf2f(v1[j]) * al[n + 1];
            acc2[j] += bf2f(v2[j]) * al[n + 2];
            acc3[j] += bf2f(v3[j]) * al[n + 3];
        }
    }
    f32x4 s = (acc0 + acc1) + (acc2 + acc3);
    *(f32x4*)(out + (size_t)b * ENC + chunk * 1024 + t * 4) = s;
}

// ---------------------------------------------------------------------------
// k2b FALLBACK: awe from fp32 encoder
// ---------------------------------------------------------------------------
__global__ __launch_bounds__(256)
void awe_kernel(const float* __restrict__ enc,
                const float* __restrict__ alpha_ws,
                float* __restrict__ out) {
    const int b = blockIdx.x, chunk = blockIdx.y;
    const int t = threadIdx.x;
    __shared__ float al[NN];
    if (t < NN) al[t] = alpha_ws[b * NN + t];
    __syncthreads();

    const float* ep = enc + (size_t)b * NN * ENC + chunk * 1024 + t * 4;
    f32x4 acc0 = {}, acc1 = {}, acc2 = {}, acc3 = {};
    #pragma unroll 2
    for (int n = 0; n < NN; n += 4) {
        f32x4 v0 = *(const f32x4*)(ep + (size_t)(n + 0) * ENC);
        f32x4 v1 = *(const f32x4*)(ep + (size_t)(n + 1) * ENC);
        f32x4 v2 = *(const f32x4*)(ep + (size_t)(n + 2) * ENC);
        f32x4 v3 = *(const f32x4*)(ep + (size_t)(n + 3) * ENC);
        acc0 += v0 * al[n];
        acc1 += v1 * al[n + 1];
        acc2 += v2 * al[n + 2];
        acc3 += v3 * al[n + 3];
    }
    f32x4 s = (acc0 + acc1) + (acc2 + acc3);
    *(f32x4*)(out + (size_t)b * ENC + chunk * 1024 + t * 4) = s;
}

// ---------------------------------------------------------------------------
extern "C" void kernel_launch(void* const* d_in, const int* in_sizes, int n_in,
                              void* d_out, int out_size, void* d_ws, size_t ws_size,
                              hipStream_t stream) {
    const float* enc    = (const float*)d_in[0];
    const float* dec    = (const float*)d_in[1];
    const float* W_enc  = (const float*)d_in[2];
    const float* b_enc  = (const float*)d_in[3];
    const float* W_dec  = (const float*)d_in[4];
    const float* b_dec  = (const float*)d_in[5];
    const float* W_full = (const float*)d_in[6];
    const float* b_full = (const float*)d_in[7];
    float* out = (float*)d_out;   // [128*2048 awe | 128*196 alpha]

    char* ws = (char*)d_ws;
    unsigned short* Wt = (unsigned short*)ws;                        // 2 MB
    float* att2     = (float*)(ws + 2097152);                        // 256 KB
    float* e_part   = (float*)(ws + 2359296);                        // 4*MM*4 = 392 KB
    float* alpha_ws = (float*)(ws + 2760704);                        // 98 KB
    unsigned short* encb = (unsigned short*)(ws + 3145728);          // 98 MB
    const size_t WS_NEED = 3145728 + (size_t)MM * ENC * 2;           // ~101 MB

    transpose_convert_kernel<<<dim3(ATT / 32, ENC / 32), 256, 0, stream>>>(W_enc, Wt);
    att2_kernel<<<dim3(BB, 8), 256, 0, stream>>>(dec, W_dec, b_dec, b_enc, att2);

    if (ws_size >= WS_NEED) {
        enc_cvt_kernel<<<MM, 256, 0, stream>>>(enc, encb);
        gemm_bf16_kernel<<<dim3(2, MM / 64), 256, 0, stream>>>(encb, Wt, att2, W_full, e_part);
        softmax_kernel<<<BB, 256, 0, stream>>>(e_part, b_full, out, alpha_ws, 2);
        awe_bf16_kernel<<<dim3(BB, 2), 256, 0, stream>>>(encb, alpha_ws, out);
    } else {
        gemm_e_kernel<<<dim3(4, MM / 64), 256, 0, stream>>>(enc, Wt, att2, W_full, e_part);
        softmax_kernel<<<BB, 256, 0, stream>>>(e_part, b_full, out, alpha_ws, 4);
        awe_kernel<<<dim3(BB, 2), 256, 0, stream>>>(enc, alpha_ws, out);
    }
}